// Round 7
// baseline (267.356 us; speedup 1.0000x reference)
//
#include <hip/hip_runtime.h>
#include <hip/hip_bf16.h>

typedef __bf16 bf16;
typedef __attribute__((ext_vector_type(4))) __bf16 bf16x4;
typedef __attribute__((ext_vector_type(8))) __bf16 bf16x8;
typedef __attribute__((ext_vector_type(4))) float f32x4;
typedef __attribute__((ext_vector_type(16))) float f32x16;

#define MFMA16x16x32 __builtin_amdgcn_mfma_f32_16x16x32_bf16
#define MFMA32 __builtin_amdgcn_mfma_f32_32x32x16_bf16

// Problem constants
#define NB 8
#define NC 512
#define NN 4096     // H*W
#define CFG 64

// -------------------- kernel 0: weight prep (fp32 -> bf16, concat) ----------
__global__ __launch_bounds__(256) void k_wprep(
    const float* __restrict__ Wf, const float* __restrict__ bfv,
    const float* __restrict__ Wg, const float* __restrict__ bgv,
    const float* __restrict__ Wh,
    bf16* __restrict__ Wfg, bf16* __restrict__ Whb, float* __restrict__ bfg)
{
    int idx = blockIdx.x * 256 + threadIdx.x;
    if (idx < 32768)       Wfg[idx] = (bf16)Wf[idx];
    else if (idx < 65536)  Wfg[idx] = (bf16)Wg[idx - 32768];
    if (idx < 262144)      Whb[idx] = (bf16)Wh[idx];
    if (idx < 64)          bfg[idx] = bfv[idx];
    else if (idx < 128)    bfg[idx] = bgv[idx - 64];
}

// -------------------- kernel 1: x [B][C][H*W] fp32 -> xT [B][N][C] bf16 -----
// grid (8, 64, 8): blockIdx.x = b  (XCD-affinity: linear%8 == b)
__global__ __launch_bounds__(256) void k_transpose(
    const float* __restrict__ x, bf16* __restrict__ xT)
{
    __shared__ bf16 tile[64][72];
    int b = blockIdx.x, n0 = blockIdx.y * 64, c0 = blockIdx.z * 64;
    int t = threadIdx.x;
    int cl  = t >> 2;
    int seg = (t & 3) * 16;
    const float* src = x + ((size_t)(b * NC + c0 + cl)) * NN + n0 + seg;
#pragma unroll
    for (int u = 0; u < 4; u++) {
        float4 v = ((const float4*)src)[u];
        tile[cl][seg + u*4 + 0] = (bf16)v.x;
        tile[cl][seg + u*4 + 1] = (bf16)v.y;
        tile[cl][seg + u*4 + 2] = (bf16)v.z;
        tile[cl][seg + u*4 + 3] = (bf16)v.w;
    }
    __syncthreads();
    int nl = t >> 2;
    int cs = (t & 3) * 16;
    bf16 buf[16];
#pragma unroll
    for (int u = 0; u < 16; u++) buf[u] = tile[cs + u][nl];
    bf16* dst = xT + ((size_t)(b * NN + n0 + nl)) * NC + c0 + cs;
    ((bf16x8*)dst)[0] = *(bf16x8*)&buf[0];
    ((bf16x8*)dst)[1] = *(bf16x8*)&buf[8];
}

// -------------------- kernel 2: fused fg+h projection GEMMs ----------------
// grid (8, 160): blockIdx.y < 32 -> fg tiles, else h tiles.
// Writers emit 32x32-MFMA fragment layouts:
//   fF/gF[b][n>>5][c>>4][(n&31)+32*((c>>3)&1)][c&7]   (c = 0..63 channel)
//   hT[b][j>>4][c>>5][(c&31)+32*((j>>3)&1)][j&7]
__global__ __launch_bounds__(256) void k_proj(
    const bf16* __restrict__ xT, const bf16* __restrict__ Wfg,
    const float* __restrict__ bfg, const bf16* __restrict__ Whb,
    const float* __restrict__ bh,
    bf16* __restrict__ fF, bf16* __restrict__ gF, bf16* __restrict__ hT)
{
    int b = blockIdx.x;
    int w = threadIdx.x >> 6, l = threadIdx.x & 63;
    int lr = l & 15, lq = l >> 4;

    if (blockIdx.y < 32) {
        // ---------------- fg: D[n][o] = xT[n][:] . Wfg[o][:] + bfg[o] -------
        int tile = blockIdx.y * 4 + w;
        int ti = tile >> 1, tj = tile & 1;       // 64 n-tiles x 2 o-tiles

        const bf16* Ab = xT + (size_t)b * NN * NC + (size_t)(ti * 64) * NC;
        const bf16* Bb = Wfg + (size_t)(tj * 64) * NC;

        f32x4 acc[4][4] = {};
        for (int k0 = 0; k0 < NC; k0 += 32) {
            bf16x8 a[4], bb[4];
#pragma unroll
            for (int fi = 0; fi < 4; fi++)
                a[fi] = *(const bf16x8*)(Ab + (size_t)(fi*16 + lr) * NC + k0 + lq*8);
#pragma unroll
            for (int fj = 0; fj < 4; fj++)
                bb[fj] = *(const bf16x8*)(Bb + (size_t)(fj*16 + lr) * NC + k0 + lq*8);
#pragma unroll
            for (int fi = 0; fi < 4; fi++)
#pragma unroll
                for (int fj = 0; fj < 4; fj++)
                    acc[fi][fj] = MFMA16x16x32(a[fi], bb[fj], acc[fi][fj], 0, 0, 0);
        }
#pragma unroll
        for (int fi = 0; fi < 4; fi++)
#pragma unroll
            for (int fj = 0; fj < 4; fj++)
#pragma unroll
                for (int t = 0; t < 4; t++) {
                    int n = ti*64 + fi*16 + lq*4 + t;      // pixel
                    int o = tj*64 + fj*16 + lr;            // out channel 0..127
                    float v = acc[fi][fj][t] + bfg[o];
                    int c = o & 63;
                    bf16* dst = (o < 64) ? fF : gF;
                    size_t off = (((size_t)(b*128 + (n>>5))*4 + (c>>4))*64
                                  + ((n&31) + 32*((c>>3)&1)))*8 + (c&7);
                    dst[off] = (bf16)v;
                }
    } else {
        // ---------------- h: D[c][j] = Whb[c][:] . xT[j][:] + bh[c] ---------
        int tile = (blockIdx.y - 32) * 4 + w;
        int ti = tile >> 6, tj = tile & 63;      // 8 c-tiles x 64 j-tiles

        const bf16* Ab = Whb + (size_t)(ti * 64) * NC;
        const bf16* Bb = xT + (size_t)b * NN * NC + (size_t)(tj * 64) * NC;

        f32x4 acc[4][4] = {};
        for (int k0 = 0; k0 < NC; k0 += 32) {
            bf16x8 a[4], bb[4];
#pragma unroll
            for (int fi = 0; fi < 4; fi++)
                a[fi] = *(const bf16x8*)(Ab + (size_t)(fi*16 + lr) * NC + k0 + lq*8);
#pragma unroll
            for (int fj = 0; fj < 4; fj++)
                bb[fj] = *(const bf16x8*)(Bb + (size_t)(fj*16 + lr) * NC + k0 + lq*8);
#pragma unroll
            for (int fi = 0; fi < 4; fi++)
#pragma unroll
                for (int fj = 0; fj < 4; fj++)
                    acc[fi][fj] = MFMA16x16x32(a[fi], bb[fj], acc[fi][fj], 0, 0, 0);
        }
#pragma unroll
        for (int fi = 0; fi < 4; fi++)
#pragma unroll
            for (int fj = 0; fj < 4; fj++)
#pragma unroll
                for (int t = 0; t < 4; t++) {
                    int c = ti*64 + fi*16 + lq*4 + t;
                    int j = tj*64 + fj*16 + lr;
                    float v = acc[fi][fj][t] + bh[c];
                    size_t off = (((size_t)(b*256 + (j>>4))*16 + (c>>5))*64
                                  + ((c&31) + 32*((j>>3)&1)))*8 + (j&7);
                    hT[off] = (bf16)v;
                }
    }
}

// -------------------- kernel 3: fused attention (32x32x16 MFMA) -------------
// grid (8, 64). Swapped S: S^T = mfma32(f, g); reg-group q of the C-frag is a
// direct bf16x4 b64 write into the PV B-frag LDS layout. PV: O^T = h . P^T.
// Per phase (128 keys): PV(p) from P[cur], S(p+1) -> P[nxt], one barrier.
__global__ __launch_bounds__(512, 4) void k_attn(
    const bf16* __restrict__ fF, const bf16* __restrict__ gF,
    const bf16* __restrict__ hT, const float* __restrict__ x,
    const float* __restrict__ gammap, float* __restrict__ out)
{
    __shared__ alignas(16) bf16 Pl[2][2][8][64][8];   // [buf][ii][ks][lane][e] = 32 KB
    __shared__ float lpart[8][32];
    __shared__ alignas(16) float linv[64];

    int b  = blockIdx.x;
    int i0 = blockIdx.y * 64;
    int w = threadIdx.x >> 6, l = threadIdx.x & 63;
    int lo = l & 31, hi = l >> 5;

    float gamma = *gammap;
    int jw = w >> 1;       // key 32-tile within phase (0..3)
    int iw = w & 1;        // query 32-half (0..1)

    bf16* Pf = &Pl[0][0][0][0][0];

    // g B-frags hoisted: gF[b][(i0>>5)+iw][kk][l][e]
    const bf16* gp = gF + ((size_t)(b*128 + (i0 >> 5) + iw)*4)*512 + (size_t)l*8;
    bf16x8 bg[4];
#pragma unroll
    for (int kk = 0; kk < 4; kk++) bg[kk] = *(const bf16x8*)(gp + kk*512);

    const bf16* fb0 = fF + (size_t)b*128*4*512 + (size_t)l*8;
    const bf16* hb0 = hT + (size_t)b*256*16*512 + (size_t)l*8;

    f32x16 oacc[2][2] = {};   // [ci][ii]
    float lsum = 0.f;

    // ---- S for phase ph -> Pl[buf] ----
#define S_STEP(ph, buf)                                                        \
    {                                                                          \
        const bf16* fb = fb0 + ((size_t)((ph)*4 + jw)*4)*512;                  \
        bf16x8 af[4];                                                          \
        _Pragma("unroll")                                                      \
        for (int kk = 0; kk < 4; kk++) af[kk] = *(const bf16x8*)(fb + kk*512); \
        f32x16 s = {};                                                         \
        _Pragma("unroll")                                                      \
        for (int kk = 0; kk < 4; kk++) s = MFMA32(af[kk], bg[kk], s, 0, 0, 0); \
        _Pragma("unroll")                                                      \
        for (int q = 0; q < 4; q++) {                                          \
            bf16x4 pq;                                                         \
            _Pragma("unroll")                                                  \
            for (int t = 0; t < 4; t++) {                                      \
                float e = __expf(s[q*4 + t]);                                  \
                lsum += e;                                                     \
                pq[t] = (bf16)e;                                               \
            }                                                                  \
            *(bf16x4*)(Pf + (buf)*8192 +                                       \
                ((iw*8 + jw*2 + (q>>1))*64 + lo + 32*(q&1))*8 + 4*hi) = pq;    \
        }                                                                      \
    }

    // ---- PV for phase ph from Pl[buf]: oacc[ci][ii] += h[ct] . P^T[ii] ----
#define PV_STEP(ph, buf)                                                       \
    {                                                                          \
        const bf16* hb = hb0 + ((size_t)(ph)*8*16)*512;                        \
        const bf16* Pr = Pf + (buf)*8192 + l*8;                                \
        __builtin_amdgcn_s_setprio(1);                                         \
        _Pragma("unroll")                                                      \
        for (int ks = 0; ks < 8; ks++) {                                       \
            bf16x8 ah0 = *(const bf16x8*)(hb + (ks*16 + w*2 + 0)*512);         \
            bf16x8 ah1 = *(const bf16x8*)(hb + (ks*16 + w*2 + 1)*512);         \
            bf16x8 bp0 = *(const bf16x8*)(Pr + (0*8 + ks)*512);                \
            bf16x8 bp1 = *(const bf16x8*)(Pr + (1*8 + ks)*512);                \
            oacc[0][0] = MFMA32(ah0, bp0, oacc[0][0], 0, 0, 0);                \
            oacc[0][1] = MFMA32(ah0, bp1, oacc[0][1], 0, 0, 0);                \
            oacc[1][0] = MFMA32(ah1, bp0, oacc[1][0], 0, 0, 0);                \
            oacc[1][1] = MFMA32(ah1, bp1, oacc[1][1], 0, 0, 0);                \
        }                                                                      \
        __builtin_amdgcn_s_setprio(0);                                         \
    }

    // prologue: S(0) -> buf 0
    S_STEP(0, 0)
    __syncthreads();

    for (int p = 0; p < 32; p++) {
        int cur = p & 1, nxt = cur ^ 1;
        PV_STEP(p, cur)
        if (p < 31) S_STEP(p + 1, nxt)
        __syncthreads();
    }
#undef S_STEP
#undef PV_STEP

    // ---- l reduction: hi/lo fold -> per-wave partials -> linv ----
    lsum += __shfl_xor(lsum, 32, 64);
    if (l < 32) lpart[w][l] = lsum;
    __syncthreads();
    if (threadIdx.x < 64) {
        int i = threadIdx.x;
        int iq = i >> 5, r = i & 31;
        linv[i] = 1.0f / (lpart[iq][r] + lpart[2 + iq][r] +
                          lpart[4 + iq][r] + lpart[6 + iq][r]);
    }
    __syncthreads();

    // ---- epilogue: out[c][i0+i] = gamma * O^T[c][i] / l[i] + x[c][i0+i] ----
    float li[2];
    li[0] = linv[lo];
    li[1] = linv[32 + lo];
    const float* xb = x + (size_t)b * NC * NN + i0;
    float* ob = out + (size_t)b * NC * NN + i0;
#pragma unroll
    for (int ci = 0; ci < 2; ci++)
#pragma unroll
        for (int ii = 0; ii < 2; ii++) {
            int c0 = w*64 + ci*32 + 4*hi;
#pragma unroll
            for (int q = 0; q < 4; q++)
#pragma unroll
                for (int t = 0; t < 4; t++) {
                    int c = c0 + q*8 + t;
                    size_t off = (size_t)c * NN + ii*32 + lo;
                    ob[off] = gamma * oacc[ci][ii][q*4 + t] * li[ii] + xb[off];
                }
        }
}

// -------------------- launcher ----------------------------------------------
extern "C" void kernel_launch(void* const* d_in, const int* in_sizes, int n_in,
                              void* d_out, int out_size, void* d_ws, size_t ws_size,
                              hipStream_t stream)
{
    const float* x     = (const float*)d_in[0];
    const float* Wf    = (const float*)d_in[1];
    const float* bf_   = (const float*)d_in[2];
    const float* Wg    = (const float*)d_in[3];
    const float* bg_   = (const float*)d_in[4];
    const float* Wh    = (const float*)d_in[5];
    const float* bh_   = (const float*)d_in[6];
    const float* gamma = (const float*)d_in[7];
    float* out = (float*)d_out;

    char* ws = (char*)d_ws;
    bf16*  xT  = (bf16*)(ws);
    bf16*  hT  = (bf16*)(ws + 33554432);
    bf16*  fF  = (bf16*)(ws + 67108864);
    bf16*  gF  = (bf16*)(ws + 71303168);
    bf16*  Wfg = (bf16*)(ws + 75497472);
    bf16*  Whb = (bf16*)(ws + 75628544);
    float* bfg = (float*)(ws + 76152832);

    k_wprep<<<dim3(1024), dim3(256), 0, stream>>>(Wf, bf_, Wg, bg_, Wh, Wfg, Whb, bfg);
    k_transpose<<<dim3(8, 64, 8), dim3(256), 0, stream>>>(x, xT);
    k_proj<<<dim3(8, 160), dim3(256), 0, stream>>>(xT, Wfg, bfg, Whb, bh_, fF, gF, hT);
    k_attn<<<dim3(8, 64), dim3(512), 0, stream>>>(fF, gF, hT, x, gamma, out);
}